// Round 5
// baseline (114.927 us; speedup 1.0000x reference)
//
#include <hip/hip_runtime.h>

#define NQ 13
#define NL 2
#define NBATCH 512
#define TPB 512
#define KDIM 16

// Fused single-qubit gate U = RZ(w2) * RY(x*w1) * RX(x*w0)
struct U2 { float r00, i00, r01, i01, r10, i10, r11, i11; };

// Index map: i (13 bits) = t[8:0] : k[3:0]. Qubit q <-> i bit 12-q.
// q0..q2 = t8..t6 (wave bits), q3..q8 = t5..t0 (lane bits), q9..q12 = k3..k0.
// CNOT chain == prefix-XOR permutation; inverse = Gray code src(j)=j^(j>>1).
// After L0 gates the state is a product state, so the chain + q0,q1,q2 gates
// reduce to a per-thread SCALAR gather; the k-part is one of two shared
// 16-vectors W0/W1. Gate q8 makes it rank-2: u*W0 + v*W1. L1 chain folds
// into measurement signs: ev[q] = sum_i (-1)^{parity(i>>(12-q))} p_pre(i).
__global__ __launch_bounds__(TPB, 4) void qsim_kernel(const float* __restrict__ x,
                                                      const float* __restrict__ w,
                                                      float* __restrict__ out) {
    __shared__ U2 ug[NL * NQ];
    __shared__ float2 sbuf[TPB];     // per-thread L0 scalar
    __shared__ float rbuf[8][NQ];

    const int b = blockIdx.x;
    const int t = threadIdx.x;
    const int lane = t & 63;
    const int wv = t >> 6;

    // ---------- Phase 0: cooperative gate-matrix computation ----------
    if (t < NL * NQ) {
        const int l = t / NQ, q = t - l * NQ;
        const float xv = x[b * NQ + q];
        const float tx = 0.5f * xv * w[(l * NQ + q) * 3 + 0];
        const float ty = 0.5f * xv * w[(l * NQ + q) * 3 + 1];
        const float tz = 0.5f * w[(l * NQ + q) * 3 + 2];
        const float cx = __cosf(tx), sx = __sinf(tx);
        const float cy = __cosf(ty), sy = __sinf(ty);
        const float cz = __cosf(tz), sz = __sinf(tz);
        const float m00r = cy * cx,  m00i = sy * sx;
        const float m01r = -sy * cx, m01i = -cy * sx;
        const float m10r = sy * cx,  m10i = -cy * sx;
        const float m11r = cy * cx,  m11i = -sy * sx;
        U2 u;
        u.r00 = m00r * cz + m00i * sz;  u.i00 = m00i * cz - m00r * sz;
        u.r01 = m01r * cz + m01i * sz;  u.i01 = m01i * cz - m01r * sz;
        u.r10 = m10r * cz - m10i * sz;  u.i10 = m10i * cz + m10r * sz;
        u.r11 = m11r * cz - m11i * sz;  u.i11 = m11i * cz + m11r * sz;
        ug[t] = u;
    }
    __syncthreads();

    // ---------- Phase 1: per-thread L0 scalar over qubits 0..8 ----------
    float cr = 1.0f, ci = 0.0f;
    #pragma unroll
    for (int q = 0; q <= 8; ++q) {            // i bit 12-q = t bit 8-q
        const U2 u = ug[q];
        const int r = (t >> (8 - q)) & 1;
        const float fr = r ? u.r10 : u.r00;
        const float fi = r ? u.i10 : u.i00;
        const float nr = cr * fr - ci * fi;
        ci = cr * fi + ci * fr;
        cr = nr;
    }
    sbuf[t] = make_float2(cr, ci);
    __syncthreads();

    // ---------- Phase 2: fused L0-chain + L1 gates q0,q1,q2 (scalar gather) ----------
    float dr = 0.0f, di = 0.0f;
    {
        const U2 u0 = ug[NQ + 0], u1 = ug[NQ + 1], u2 = ug[NQ + 2];
        const int r0 = (t >> 8) & 1, r1 = (t >> 7) & 1, r2 = (t >> 6) & 1;
        const float A0r = r0 ? u0.r10 : u0.r00, A0i = r0 ? u0.i10 : u0.i00;
        const float A1r = r0 ? u0.r11 : u0.r01, A1i = r0 ? u0.i11 : u0.i01;
        const float B0r = r1 ? u1.r10 : u1.r00, B0i = r1 ? u1.i10 : u1.i00;
        const float B1r = r1 ? u1.r11 : u1.r01, B1i = r1 ? u1.i11 : u1.i01;
        const float C0r = r2 ? u2.r10 : u2.r00, C0i = r2 ? u2.i10 : u2.i00;
        const float C1r = r2 ? u2.r11 : u2.r01, C1i = r2 ? u2.i11 : u2.i01;
        float ABr[4], ABi[4];
        ABr[0] = A0r * B0r - A0i * B0i;  ABi[0] = A0r * B0i + A0i * B0r;
        ABr[1] = A0r * B1r - A0i * B1i;  ABi[1] = A0r * B1i + A0i * B1r;
        ABr[2] = A1r * B0r - A1i * B0i;  ABi[2] = A1r * B0i + A1i * B0r;
        ABr[3] = A1r * B1r - A1i * B1i;  ABi[3] = A1r * B1i + A1i * B1r;
        const int gl = (t ^ (t >> 1)) & 31;    // gray of t bits 0..4 (uses t5)
        const int t5 = (t >> 5) & 1;
        #pragma unroll
        for (int s = 0; s < 8; ++s) {          // s = (a<<2)|(b<<1)|c
            const int a = s >> 2, bb = (s >> 1) & 1, c = s & 1;
            const int src = (a << 8) | ((a ^ bb) << 7) | ((bb ^ c) << 6)
                          | ((c ^ t5) << 5) | gl;
            const float2 v = sbuf[src];
            const float cRr = c ? C1r : C0r, cRi = c ? C1i : C0i;
            const float kr = ABr[a * 2 + bb] * cRr - ABi[a * 2 + bb] * cRi;
            const float ki = ABr[a * 2 + bb] * cRi + ABi[a * 2 + bb] * cRr;
            dr += kr * v.x - ki * v.y;
            di += kr * v.y + ki * v.x;
        }
    }

    // ---------- Phase 3: L1 lane-bit gates q3..q7 (scalar shuffles) ----------
    #pragma unroll
    for (int q = 3; q <= 7; ++q) {
        const U2 u = ug[NQ + q];
        const int m = 1 << (8 - q);            // 32,16,8,4,2
        const int bit = (lane >> (8 - q)) & 1;
        const float a0r = bit ? u.r11 : u.r00, a0i = bit ? u.i11 : u.i00;
        const float b0r = bit ? u.r10 : u.r01, b0i = bit ? u.i10 : u.i01;
        const float pr = __shfl_xor(dr, m, 64);
        const float pi = __shfl_xor(di, m, 64);
        const float nr = a0r * dr - a0i * di + b0r * pr - b0i * pi;
        di = a0r * di + a0i * dr + b0r * pi + b0i * pr;
        dr = nr;
    }

    // ---------- Phase 4: L1 gate q8 (t bit 0) -> rank-2 coefficients ----------
    float uur, uui, vvr, vvi;                  // state = uu*W0(k) + vv*W1(k)
    {
        const U2 u8 = ug[NQ + 8];
        const float pr = __shfl_xor(dr, 1, 64);
        const float pi = __shfl_xor(di, 1, 64);
        const int t0 = t & 1;
        const float o1r = t0 ? pr : dr, o1i = t0 ? pi : di;   // W0 operand
        const float o2r = t0 ? dr : pr, o2i = t0 ? di : pi;   // W1 operand
        const float c1r = t0 ? u8.r10 : u8.r00, c1i = t0 ? u8.i10 : u8.i00;
        const float c2r = t0 ? u8.r11 : u8.r01, c2i = t0 ? u8.i11 : u8.i01;
        uur = c1r * o1r - c1i * o1i;  uui = c1r * o1i + c1i * o1r;
        vvr = c2r * o2r - c2i * o2i;  vvi = c2r * o2i + c2i * o2r;
    }

    // ---------- Phase 5: k-space (shared across threads, in registers) ----------
    // kprod = L0 gates q9..q12 on |0000>
    float kpr[KDIM], kpi[KDIM];
    kpr[0] = 1.0f; kpi[0] = 0.0f;
    #pragma unroll
    for (int j = 0; j < 4; ++j) {              // k bit j <-> qubit 12-j, layer 0
        const U2 u = ug[12 - j];
        const int m = 1 << j;
        #pragma unroll
        for (int kk = 0; kk < 8; ++kk) {
            if (kk < m) {
                const float ar = kpr[kk], ai = kpi[kk];
                kpr[kk + m] = ar * u.r10 - ai * u.i10;
                kpi[kk + m] = ar * u.i10 + ai * u.r10;
                kpr[kk]     = ar * u.r00 - ai * u.i00;
                kpi[kk]     = ar * u.i00 + ai * u.r00;
            }
        }
    }
    // W_p(k) = kprod[gray(k) ^ (p<<3)]
    float w0r[KDIM], w0i[KDIM], w1r[KDIM], w1i[KDIM];
    #pragma unroll
    for (int k = 0; k < KDIM; ++k) {
        const int g = k ^ (k >> 1);
        w0r[k] = kpr[g];      w0i[k] = kpi[g];
        w1r[k] = kpr[g ^ 8];  w1i[k] = kpi[g ^ 8];
    }
    // L1 gates q9..q12 applied to both k-vectors
    #pragma unroll
    for (int j = 3; j >= 0; --j) {             // qubit 9+(3-j) <-> k bit j
        const U2 u = ug[NQ + 12 - j];
        const int m = 1 << j;
        #pragma unroll
        for (int k = 0; k < KDIM; ++k) {
            if (((k >> j) & 1) == 0) {
                const int k1 = k | m;
                {
                    const float ar = w0r[k], ai = w0i[k], br = w0r[k1], bi = w0i[k1];
                    w0r[k]  = u.r00 * ar - u.i00 * ai + u.r01 * br - u.i01 * bi;
                    w0i[k]  = u.r00 * ai + u.i00 * ar + u.r01 * bi + u.i01 * br;
                    w0r[k1] = u.r10 * ar - u.i10 * ai + u.r11 * br - u.i11 * bi;
                    w0i[k1] = u.r10 * ai + u.i10 * ar + u.r11 * bi + u.i11 * br;
                }
                {
                    const float ar = w1r[k], ai = w1i[k], br = w1r[k1], bi = w1i[k1];
                    w1r[k]  = u.r00 * ar - u.i00 * ai + u.r01 * br - u.i01 * bi;
                    w1i[k]  = u.r00 * ai + u.i00 * ar + u.r01 * bi + u.i01 * br;
                    w1r[k1] = u.r10 * ar - u.i10 * ai + u.r11 * br - u.i11 * bi;
                    w1i[k1] = u.r10 * ai + u.i10 * ar + u.r11 * bi + u.i11 * br;
                }
            }
        }
    }

    // ---------- Phase 6: measurement, L1 chain folded into signs ----------
    float S0 = 0.f, S1 = 0.f, Sr = 0.f, Si = 0.f;
    float T0[4] = {0,0,0,0}, T1[4] = {0,0,0,0}, Tr[4] = {0,0,0,0}, Ti[4] = {0,0,0,0};
    #pragma unroll
    for (int k = 0; k < KDIM; ++k) {
        const float p0 = w0r[k] * w0r[k] + w0i[k] * w0i[k];
        const float p1 = w1r[k] * w1r[k] + w1i[k] * w1i[k];
        const float rr = w0r[k] * w1r[k] + w0i[k] * w1i[k];
        const float ri = w0i[k] * w1r[k] - w0r[k] * w1i[k];
        S0 += p0; S1 += p1; Sr += rr; Si += ri;
        #pragma unroll
        for (int idx = 0; idx < 4; ++idx) {    // qubit 9+idx: parity(k >> (3-idx))
            if (__popc(k >> (3 - idx)) & 1) {
                T0[idx] -= p0; T1[idx] -= p1; Tr[idx] -= rr; Ti[idx] -= ri;
            } else {
                T0[idx] += p0; T1[idx] += p1; Tr[idx] += rr; Ti[idx] += ri;
            }
        }
    }
    const float A = uur * uur + uui * uui;
    const float B = vvr * vvr + vvi * vvi;
    const float C = 2.0f * (uur * vvr + uui * vvi);
    const float D = -2.0f * (uui * vvr - uur * vvi);
    const float ptot = A * S0 + B * S1 + C * Sr + D * Si;
    float ev[NQ];
    #pragma unroll
    for (int q = 0; q <= 8; ++q)
        ev[q] = (__popc(t >> (8 - q)) & 1) ? -ptot : ptot;
    const int pt = __popc(t) & 1;
    #pragma unroll
    for (int idx = 0; idx < 4; ++idx) {
        const float vq = A * T0[idx] + B * T1[idx] + C * Tr[idx] + D * Ti[idx];
        ev[9 + idx] = pt ? -vq : vq;
    }

    // ---------- reduction ----------
    #pragma unroll
    for (int q = 0; q < NQ; ++q) {
        float vv = ev[q];
        #pragma unroll
        for (int off = 32; off; off >>= 1) vv += __shfl_xor(vv, off, 64);
        ev[q] = vv;
    }
    if (lane == 0) {
        #pragma unroll
        for (int q = 0; q < NQ; ++q) rbuf[wv][q] = ev[q];
    }
    __syncthreads();
    if (t < NQ) {
        float s = 0.0f;
        #pragma unroll
        for (int wvv = 0; wvv < 8; ++wvv) s += rbuf[wvv][t];
        out[b * NQ + t] = s;
    }
}

extern "C" void kernel_launch(void* const* d_in, const int* in_sizes, int n_in,
                              void* d_out, int out_size, void* d_ws, size_t ws_size,
                              hipStream_t stream) {
    const float* x = (const float*)d_in[0];   // (512, 13) float32
    const float* w = (const float*)d_in[1];   // (2, 13, 3) float32
    float* out = (float*)d_out;               // (512, 13) float32
    qsim_kernel<<<NBATCH, TPB, 0, stream>>>(x, w, out);
}

// Round 6
// 60.761 us; speedup vs baseline: 1.8915x; 1.8915x over previous
//
#include <hip/hip_runtime.h>

#define NQ 13
#define NL 2
#define NBATCH 512
#define TPB 512

// Fused single-qubit gate U = RZ(w2) * RY(x*w1) * RX(x*w0)
struct U2 { float r00, i00, r01, i01, r10, i10, r11, i11; };

// Index map: i (13 bits) = t[8:0] : k[3:0]. Qubit q <-> i bit 12-q.
// q0..q2 = t8..t6, q3..q8 = t5..t0 (lane bits), q9..q12 = k3..k0.
// CNOT chain == prefix-XOR permutation; inverse = Gray code src(j)=j^(j>>1).
// After L0 the state is a product state: chain + L1 gates q0..q2 collapse to a
// per-thread scalar gather; k-part is rank-2 (uu*W0 + vv*W1) after gate q8.
// L1 chain folds into measurement signs. K-space (block-uniform) is computed
// by wave 0 only -> 20 scalars in LDS (this was the v5 spill source).
__global__ __launch_bounds__(TPB, 4) void qsim_kernel(const float* __restrict__ x,
                                                      const float* __restrict__ w,
                                                      float* __restrict__ out) {
    __shared__ U2 ug[NL * NQ];
    __shared__ float2 sbuf[TPB];     // per-thread L0 scalar
    __shared__ float scal[20];       // S0,S1,Sr,Si, then T0,T1,Tr,Ti per k-qubit
    __shared__ float rbuf[8][11];    // per-wave reduction partials

    const int b = blockIdx.x;
    const int t = threadIdx.x;
    const int lane = t & 63;
    const int wv = t >> 6;

    // ---------- Phase 0: cooperative gate-matrix computation ----------
    if (t < NL * NQ) {
        const int l = t / NQ, q = t - l * NQ;
        const float xv = x[b * NQ + q];
        const float tx = 0.5f * xv * w[(l * NQ + q) * 3 + 0];
        const float ty = 0.5f * xv * w[(l * NQ + q) * 3 + 1];
        const float tz = 0.5f * w[(l * NQ + q) * 3 + 2];
        const float cx = __cosf(tx), sx = __sinf(tx);
        const float cy = __cosf(ty), sy = __sinf(ty);
        const float cz = __cosf(tz), sz = __sinf(tz);
        const float m00r = cy * cx,  m00i = sy * sx;
        const float m01r = -sy * cx, m01i = -cy * sx;
        const float m10r = sy * cx,  m10i = -cy * sx;
        const float m11r = cy * cx,  m11i = -sy * sx;
        U2 u;
        u.r00 = m00r * cz + m00i * sz;  u.i00 = m00i * cz - m00r * sz;
        u.r01 = m01r * cz + m01i * sz;  u.i01 = m01i * cz - m01r * sz;
        u.r10 = m10r * cz - m10i * sz;  u.i10 = m10i * cz + m10r * sz;
        u.r11 = m11r * cz - m11i * sz;  u.i11 = m11i * cz + m11r * sz;
        ug[t] = u;
    }
    __syncthreads();

    // ---------- Phase 1: per-thread L0 scalar over qubits 0..8 ----------
    float cr = 1.0f, ci = 0.0f;
    #pragma unroll
    for (int q = 0; q <= 8; ++q) {            // i bit 12-q = t bit 8-q
        const U2 u = ug[q];
        const int r = (t >> (8 - q)) & 1;
        const float fr = r ? u.r10 : u.r00;
        const float fi = r ? u.i10 : u.i00;
        const float nr = cr * fr - ci * fi;
        ci = cr * fi + ci * fr;
        cr = nr;
    }
    sbuf[t] = make_float2(cr, ci);

    // ---------- KS phase (wave 0 only): block-uniform k-space scalars ----------
    if (wv == 0) {
        const int k = lane & 15;              // replicated across 4 sixteen-lane groups
        const int g = k ^ (k >> 1);
        // kprod common part: bits 0..2 of g (qubits 12,11,10)
        float pr = 1.0f, pi = 0.0f;
        #pragma unroll
        for (int j = 0; j < 3; ++j) {
            const U2 u = ug[12 - j];
            const int r = (g >> j) & 1;
            const float fr = r ? u.r10 : u.r00;
            const float fi = r ? u.i10 : u.i00;
            const float nr = pr * fr - pi * fi;
            pi = pr * fi + pi * fr;
            pr = nr;
        }
        const U2 u9 = ug[9];                  // qubit 9 <-> k bit 3
        const int g3 = (g >> 3) & 1;
        const float f0r = g3 ? u9.r10 : u9.r00, f0i = g3 ? u9.i10 : u9.i00;
        const float f1r = g3 ? u9.r00 : u9.r10, f1i = g3 ? u9.i00 : u9.i10;
        float w0r = pr * f0r - pi * f0i, w0i = pr * f0i + pi * f0r;   // W0(k)=kprod[g]
        float w1r = pr * f1r - pi * f1i, w1i = pr * f1i + pi * f1r;   // W1(k)=kprod[g^8]
        // L1 gates q9..q12 on k-space (qubit 12-j <-> k bit j)
        #pragma unroll
        for (int j = 3; j >= 0; --j) {
            const U2 u = ug[NQ + 12 - j];
            const int m = 1 << j;
            const int bit = (k >> j) & 1;
            const float a0r = bit ? u.r10 : u.r00, a0i = bit ? u.i10 : u.i00;
            const float a1r = bit ? u.r11 : u.r01, a1i = bit ? u.i11 : u.i01;
            {
                const float qr = __shfl_xor(w0r, m, 64);
                const float qi = __shfl_xor(w0i, m, 64);
                const float v0r = bit ? qr : w0r, v0i = bit ? qi : w0i;
                const float v1r = bit ? w0r : qr, v1i = bit ? w0i : qi;
                w0r = a0r * v0r - a0i * v0i + a1r * v1r - a1i * v1i;
                w0i = a0r * v0i + a0i * v0r + a1r * v1i + a1i * v1r;
            }
            {
                const float qr = __shfl_xor(w1r, m, 64);
                const float qi = __shfl_xor(w1i, m, 64);
                const float v0r = bit ? qr : w1r, v0i = bit ? qi : w1i;
                const float v1r = bit ? w1r : qr, v1i = bit ? w1i : qi;
                w1r = a0r * v0r - a0i * v0i + a1r * v1r - a1i * v1i;
                w1i = a0r * v0i + a0i * v0r + a1r * v1i + a1i * v1r;
            }
        }
        // products and suffix-parity reduction over the 4 k-bits
        float tr0[5], tr1[5], tr2[5], tr3[5];
        tr0[0] = w0r * w0r + w0i * w0i;       // p0
        tr1[0] = w1r * w1r + w1i * w1i;       // p1
        tr2[0] = w0r * w1r + w0i * w1i;       // rr
        tr3[0] = w0i * w1r - w0r * w1i;       // ri
        #pragma unroll
        for (int j = 3; j >= 0; --j) {
            const int m = 1 << j;
            const int neg = (k >> j) & 1;
            const int cnt = 4 - j;            // items before this step
            {
                const float pre = tr0[cnt - 1];
                const float pp = __shfl_xor(pre, m, 64);
                tr0[cnt] = neg ? (pp - pre) : (pre - pp);
                tr0[cnt - 1] = pre + pp;
                #pragma unroll
                for (int e = 0; e < 4; ++e)
                    if (e < cnt - 1) tr0[e] += __shfl_xor(tr0[e], m, 64);
            }
            {
                const float pre = tr1[cnt - 1];
                const float pp = __shfl_xor(pre, m, 64);
                tr1[cnt] = neg ? (pp - pre) : (pre - pp);
                tr1[cnt - 1] = pre + pp;
                #pragma unroll
                for (int e = 0; e < 4; ++e)
                    if (e < cnt - 1) tr1[e] += __shfl_xor(tr1[e], m, 64);
            }
            {
                const float pre = tr2[cnt - 1];
                const float pp = __shfl_xor(pre, m, 64);
                tr2[cnt] = neg ? (pp - pre) : (pre - pp);
                tr2[cnt - 1] = pre + pp;
                #pragma unroll
                for (int e = 0; e < 4; ++e)
                    if (e < cnt - 1) tr2[e] += __shfl_xor(tr2[e], m, 64);
            }
            {
                const float pre = tr3[cnt - 1];
                const float pp = __shfl_xor(pre, m, 64);
                tr3[cnt] = neg ? (pp - pre) : (pre - pp);
                tr3[cnt - 1] = pre + pp;
                #pragma unroll
                for (int e = 0; e < 4; ++e)
                    if (e < cnt - 1) tr3[e] += __shfl_xor(tr3[e], m, 64);
            }
        }
        if (lane == 0) {
            scal[0] = tr0[0]; scal[1] = tr1[0]; scal[2] = tr2[0]; scal[3] = tr3[0];
            #pragma unroll
            for (int idx = 0; idx < 4; ++idx) {
                scal[4 + idx * 4 + 0] = tr0[1 + idx];
                scal[4 + idx * 4 + 1] = tr1[1 + idx];
                scal[4 + idx * 4 + 2] = tr2[1 + idx];
                scal[4 + idx * 4 + 3] = tr3[1 + idx];
            }
        }
    }
    __syncthreads();                           // sbuf + scal ready

    // ---------- Phase 2: fused L0-chain + L1 gates q0,q1,q2 (scalar gather) ----------
    float dr = 0.0f, di = 0.0f;
    {
        const U2 u0 = ug[NQ + 0], u1 = ug[NQ + 1], u2 = ug[NQ + 2];
        const int r0 = (t >> 8) & 1, r1 = (t >> 7) & 1, r2 = (t >> 6) & 1;
        const float A0r = r0 ? u0.r10 : u0.r00, A0i = r0 ? u0.i10 : u0.i00;
        const float A1r = r0 ? u0.r11 : u0.r01, A1i = r0 ? u0.i11 : u0.i01;
        const float B0r = r1 ? u1.r10 : u1.r00, B0i = r1 ? u1.i10 : u1.i00;
        const float B1r = r1 ? u1.r11 : u1.r01, B1i = r1 ? u1.i11 : u1.i01;
        const float C0r = r2 ? u2.r10 : u2.r00, C0i = r2 ? u2.i10 : u2.i00;
        const float C1r = r2 ? u2.r11 : u2.r01, C1i = r2 ? u2.i11 : u2.i01;
        float ABr[4], ABi[4];
        ABr[0] = A0r * B0r - A0i * B0i;  ABi[0] = A0r * B0i + A0i * B0r;
        ABr[1] = A0r * B1r - A0i * B1i;  ABi[1] = A0r * B1i + A0i * B1r;
        ABr[2] = A1r * B0r - A1i * B0i;  ABi[2] = A1r * B0i + A1i * B0r;
        ABr[3] = A1r * B1r - A1i * B1i;  ABi[3] = A1r * B1i + A1i * B1r;
        const int gl = (t ^ (t >> 1)) & 31;
        const int t5 = (t >> 5) & 1;
        #pragma unroll
        for (int s = 0; s < 8; ++s) {          // s = (a<<2)|(bb<<1)|c
            const int a = s >> 2, bb = (s >> 1) & 1, c = s & 1;
            const int src = (a << 8) | ((a ^ bb) << 7) | ((bb ^ c) << 6)
                          | ((c ^ t5) << 5) | gl;
            const float2 v = sbuf[src];
            const float cRr = c ? C1r : C0r, cRi = c ? C1i : C0i;
            const float kr = ABr[a * 2 + bb] * cRr - ABi[a * 2 + bb] * cRi;
            const float ki = ABr[a * 2 + bb] * cRi + ABi[a * 2 + bb] * cRr;
            dr += kr * v.x - ki * v.y;
            di += kr * v.y + ki * v.x;
        }
    }

    // ---------- Phase 3: L1 lane-bit gates q3..q7 ----------
    #pragma unroll
    for (int q = 3; q <= 7; ++q) {
        const U2 u = ug[NQ + q];
        const int m = 1 << (8 - q);            // 32,16,8,4,2
        const int bit = (lane >> (8 - q)) & 1;
        const float a0r = bit ? u.r11 : u.r00, a0i = bit ? u.i11 : u.i00;
        const float b0r = bit ? u.r10 : u.r01, b0i = bit ? u.i10 : u.i01;
        const float pr = __shfl_xor(dr, m, 64);
        const float pi = __shfl_xor(di, m, 64);
        const float nr = a0r * dr - a0i * di + b0r * pr - b0i * pi;
        di = a0r * di + a0i * dr + b0r * pi + b0i * pr;
        dr = nr;
    }

    // ---------- Phase 4: L1 gate q8 (t bit 0) -> rank-2 coefficients ----------
    float uur, uui, vvr, vvi;                  // state = uu*W0(k) + vv*W1(k)
    {
        const U2 u8 = ug[NQ + 8];
        const float pr = __shfl_xor(dr, 1, 64);
        const float pi = __shfl_xor(di, 1, 64);
        const int t0 = t & 1;
        const float o1r = t0 ? pr : dr, o1i = t0 ? pi : di;
        const float o2r = t0 ? dr : pr, o2i = t0 ? di : pi;
        const float c1r = t0 ? u8.r10 : u8.r00, c1i = t0 ? u8.i10 : u8.i00;
        const float c2r = t0 ? u8.r11 : u8.r01, c2i = t0 ? u8.i11 : u8.i01;
        uur = c1r * o1r - c1i * o1i;  uui = c1r * o1i + c1i * o1r;
        vvr = c2r * o2r - c2i * o2i;  vvi = c2r * o2i + c2i * o2r;
    }

    // ---------- Phase 5: per-thread ptot + lane-level reductions ----------
    const float A = uur * uur + uui * uui;
    const float B = vvr * vvr + vvi * vvi;
    const float C = 2.0f * (uur * vvr + uui * vvi);
    const float D = -2.0f * (uui * vvr - uur * vvi);
    const float ptot = A * scal[0] + B * scal[1] + C * scal[2] + D * scal[3];

    const float sg = (__popc(lane) & 1) ? -1.0f : 1.0f;
    float rA = sg * A, rB = sg * B, rC = sg * C, rD = sg * D;
    float trV[7];
    trV[0] = ptot;
    #pragma unroll
    for (int j = 5; j >= 0; --j) {
        const int m = 1 << j;
        const int neg = (lane >> j) & 1;
        const int cnt = 6 - j;                 // items before this step
        const float pre = trV[cnt - 1];
        const float pp = __shfl_xor(pre, m, 64);
        trV[cnt] = neg ? (pp - pre) : (pre - pp);
        trV[cnt - 1] = pre + pp;
        #pragma unroll
        for (int e = 0; e < 6; ++e)
            if (e < cnt - 1) trV[e] += __shfl_xor(trV[e], m, 64);
        rA += __shfl_xor(rA, m, 64);
        rB += __shfl_xor(rB, m, 64);
        rC += __shfl_xor(rC, m, 64);
        rD += __shfl_xor(rD, m, 64);
    }
    if (lane == 0) {
        #pragma unroll
        for (int e = 0; e < 7; ++e) rbuf[wv][e] = trV[e];
        rbuf[wv][7] = rA; rbuf[wv][8] = rB; rbuf[wv][9] = rC; rbuf[wv][10] = rD;
    }
    __syncthreads();

    // ---------- Phase 6: cross-wave combine (13 threads) ----------
    if (t < NQ) {
        float s = 0.0f;
        if (t <= 2) {
            #pragma unroll
            for (int wvv = 0; wvv < 8; ++wvv)
                s += (__popc(wvv >> (2 - t)) & 1) ? -rbuf[wvv][0] : rbuf[wvv][0];
        } else if (t <= 8) {
            #pragma unroll
            for (int wvv = 0; wvv < 8; ++wvv)
                s += (__popc(wvv) & 1) ? -rbuf[wvv][t - 2] : rbuf[wvv][t - 2];
        } else {
            const int idx = t - 9;
            float SA = 0.f, SB = 0.f, SC = 0.f, SD = 0.f;
            #pragma unroll
            for (int wvv = 0; wvv < 8; ++wvv) {
                const float sgn = (__popc(wvv) & 1) ? -1.0f : 1.0f;
                SA += sgn * rbuf[wvv][7];  SB += sgn * rbuf[wvv][8];
                SC += sgn * rbuf[wvv][9];  SD += sgn * rbuf[wvv][10];
            }
            s = SA * scal[4 + idx * 4 + 0] + SB * scal[4 + idx * 4 + 1]
              + SC * scal[4 + idx * 4 + 2] + SD * scal[4 + idx * 4 + 3];
        }
        out[b * NQ + t] = s;
    }
}

extern "C" void kernel_launch(void* const* d_in, const int* in_sizes, int n_in,
                              void* d_out, int out_size, void* d_ws, size_t ws_size,
                              hipStream_t stream) {
    const float* x = (const float*)d_in[0];   // (512, 13) float32
    const float* w = (const float*)d_in[1];   // (2, 13, 3) float32
    float* out = (float*)d_out;               // (512, 13) float32
    qsim_kernel<<<NBATCH, TPB, 0, stream>>>(x, w, out);
}

// Round 7
// 58.750 us; speedup vs baseline: 1.9562x; 1.0342x over previous
//
#include <hip/hip_runtime.h>

#define NQ 13
#define NL 2
#define NBATCH 512
#define TPB 512

// Fused single-qubit gate U = RZ(w2) * RY(x*w1) * RX(x*w0)
struct U2 { float r00, i00, r01, i01, r10, i10, r11, i11; };

// Index map: i (13 bits) = t[8:0] : k[3:0]. Qubit q <-> i bit 12-q.
// q0..q2 = t8..t6, q3..q8 = t5..t0 (lane bits), q9..q12 = k3..k0.
// CNOT chain == prefix-XOR permutation; inverse = Gray code src(j)=j^(j>>1).
// After L0 the state is a product state: chain + L1 gates q0..q2 collapse to a
// per-thread scalar gather; k-part is rank-2 (uu*W0 + vv*W1) after gate q8.
// L1 chain folds into measurement signs: ev[q] = sum_t parity(t>>(8-q)) ptot(t).
// K-space (block-uniform) computed by wave 0's four 16-lane groups -> 20 LDS
// scalars. Final 13 outputs: one/two per wave via LDS gather + 6-shfl butterfly.
__global__ __launch_bounds__(TPB, 4) void qsim_kernel(const float* __restrict__ x,
                                                      const float* __restrict__ w,
                                                      float* __restrict__ out) {
    __shared__ U2 ug[NL * NQ];
    __shared__ float2 sbuf[TPB];     // per-thread L0 scalar
    __shared__ float scal[20];       // S0,S1,Sr,Si then {T0,T1,Tr,Ti} per k-qubit
    __shared__ float pbuf[TPB];      // per-thread ptot
    __shared__ float abuf0[TPB];     // parity-signed A
    __shared__ float abuf1[TPB];     // parity-signed B
    __shared__ float abuf2[TPB];     // parity-signed C
    __shared__ float abuf3[TPB];     // parity-signed D

    const int b = blockIdx.x;
    const int t = threadIdx.x;
    const int lane = t & 63;
    const int wv = t >> 6;

    // ---------- Phase 0: cooperative gate-matrix computation ----------
    if (t < NL * NQ) {
        const int l = t / NQ, q = t - l * NQ;
        const float xv = x[b * NQ + q];
        const float tx = 0.5f * xv * w[(l * NQ + q) * 3 + 0];
        const float ty = 0.5f * xv * w[(l * NQ + q) * 3 + 1];
        const float tz = 0.5f * w[(l * NQ + q) * 3 + 2];
        const float cx = __cosf(tx), sx = __sinf(tx);
        const float cy = __cosf(ty), sy = __sinf(ty);
        const float cz = __cosf(tz), sz = __sinf(tz);
        const float m00r = cy * cx,  m00i = sy * sx;
        const float m01r = -sy * cx, m01i = -cy * sx;
        const float m10r = sy * cx,  m10i = -cy * sx;
        const float m11r = cy * cx,  m11i = -sy * sx;
        U2 u;
        u.r00 = m00r * cz + m00i * sz;  u.i00 = m00i * cz - m00r * sz;
        u.r01 = m01r * cz + m01i * sz;  u.i01 = m01i * cz - m01r * sz;
        u.r10 = m10r * cz - m10i * sz;  u.i10 = m10i * cz + m10r * sz;
        u.r11 = m11r * cz - m11i * sz;  u.i11 = m11i * cz + m11r * sz;
        ug[t] = u;
    }
    __syncthreads();

    // ---------- Phase 1: per-thread L0 scalar over qubits 0..8 ----------
    float cr = 1.0f, ci = 0.0f;
    #pragma unroll
    for (int q = 0; q <= 8; ++q) {            // i bit 12-q = t bit 8-q
        const U2 u = ug[q];
        const int r = (t >> (8 - q)) & 1;
        const float fr = r ? u.r10 : u.r00;
        const float fi = r ? u.i10 : u.i00;
        const float nr = cr * fr - ci * fi;
        ci = cr * fi + ci * fr;
        cr = nr;
    }
    sbuf[t] = make_float2(cr, ci);

    // ---------- KS phase (wave 0): block-uniform k-space scalars ----------
    // Lane = g*16 + k; group g reduces one of {p0,p1,rr,ri}.
    if (wv == 0) {
        const int k = lane & 15;
        const int g = lane >> 4;
        const int gy = k ^ (k >> 1);
        float pr = 1.0f, pi = 0.0f;
        #pragma unroll
        for (int j = 0; j < 3; ++j) {          // qubits 12,11,10 <-> g bits 0..2
            const U2 u = ug[12 - j];
            const int r = (gy >> j) & 1;
            const float fr = r ? u.r10 : u.r00;
            const float fi = r ? u.i10 : u.i00;
            const float nr = pr * fr - pi * fi;
            pi = pr * fi + pi * fr;
            pr = nr;
        }
        const U2 u9 = ug[9];                  // qubit 9 <-> k bit 3
        const int g3 = (gy >> 3) & 1;
        const float f0r = g3 ? u9.r10 : u9.r00, f0i = g3 ? u9.i10 : u9.i00;
        const float f1r = g3 ? u9.r00 : u9.r10, f1i = g3 ? u9.i00 : u9.i10;
        float w0r = pr * f0r - pi * f0i, w0i = pr * f0i + pi * f0r;   // W0=kprod[g]
        float w1r = pr * f1r - pi * f1i, w1i = pr * f1i + pi * f1r;   // W1=kprod[g^8]
        // L1 gates q9..q12 on k-space (qubit 12-j <-> k bit j)
        #pragma unroll
        for (int j = 3; j >= 0; --j) {
            const U2 u = ug[NQ + 12 - j];
            const int m = 1 << j;
            const int bit = (k >> j) & 1;
            const float a0r = bit ? u.r10 : u.r00, a0i = bit ? u.i10 : u.i00;
            const float a1r = bit ? u.r11 : u.r01, a1i = bit ? u.i11 : u.i01;
            {
                const float qr = __shfl_xor(w0r, m, 64);
                const float qi = __shfl_xor(w0i, m, 64);
                const float v0r = bit ? qr : w0r, v0i = bit ? qi : w0i;
                const float v1r = bit ? w0r : qr, v1i = bit ? w0i : qi;
                w0r = a0r * v0r - a0i * v0i + a1r * v1r - a1i * v1i;
                w0i = a0r * v0i + a0i * v0r + a1r * v1i + a1i * v1r;
            }
            {
                const float qr = __shfl_xor(w1r, m, 64);
                const float qi = __shfl_xor(w1i, m, 64);
                const float v0r = bit ? qr : w1r, v0i = bit ? qi : w1i;
                const float v1r = bit ? w1r : qr, v1i = bit ? w1i : qi;
                w1r = a0r * v0r - a0i * v0i + a1r * v1r - a1i * v1i;
                w1i = a0r * v0i + a0i * v0r + a1r * v1i + a1i * v1r;
            }
        }
        // group-local quantity
        const float p0v = w0r * w0r + w0i * w0i;
        const float p1v = w1r * w1r + w1i * w1i;
        const float rrv = w0r * w1r + w0i * w1i;
        const float riv = w0i * w1r - w0r * w1i;
        float tr[5];
        tr[0] = (g == 0) ? p0v : (g == 1) ? p1v : (g == 2) ? rrv : riv;
        // suffix-parity reduction over 4 k-bits (within the 16-lane group)
        #pragma unroll
        for (int j = 3; j >= 0; --j) {
            const int m = 1 << j;
            const int neg = (k >> j) & 1;
            const int cnt = 4 - j;
            const float pre = tr[cnt - 1];
            const float pp = __shfl_xor(pre, m, 64);
            tr[cnt] = neg ? (pp - pre) : (pre - pp);
            tr[cnt - 1] = pre + pp;
            #pragma unroll
            for (int e = 0; e < 4; ++e)
                if (e < cnt - 1) tr[e] += __shfl_xor(tr[e], m, 64);
        }
        if (k == 0) {
            scal[g] = tr[0];
            #pragma unroll
            for (int idx = 0; idx < 4; ++idx)
                scal[4 + idx * 4 + g] = tr[1 + idx];
        }
    }
    __syncthreads();                           // sbuf + scal ready

    // ---------- Phase 2: fused L0-chain + L1 gates q0,q1,q2 (scalar gather) ----------
    float dr = 0.0f, di = 0.0f;
    {
        const U2 u0 = ug[NQ + 0], u1 = ug[NQ + 1], u2 = ug[NQ + 2];
        const int r0 = (t >> 8) & 1, r1 = (t >> 7) & 1, r2 = (t >> 6) & 1;
        const float A0r = r0 ? u0.r10 : u0.r00, A0i = r0 ? u0.i10 : u0.i00;
        const float A1r = r0 ? u0.r11 : u0.r01, A1i = r0 ? u0.i11 : u0.i01;
        const float B0r = r1 ? u1.r10 : u1.r00, B0i = r1 ? u1.i10 : u1.i00;
        const float B1r = r1 ? u1.r11 : u1.r01, B1i = r1 ? u1.i11 : u1.i01;
        const float C0r = r2 ? u2.r10 : u2.r00, C0i = r2 ? u2.i10 : u2.i00;
        const float C1r = r2 ? u2.r11 : u2.r01, C1i = r2 ? u2.i11 : u2.i01;
        float ABr[4], ABi[4];
        ABr[0] = A0r * B0r - A0i * B0i;  ABi[0] = A0r * B0i + A0i * B0r;
        ABr[1] = A0r * B1r - A0i * B1i;  ABi[1] = A0r * B1i + A0i * B1r;
        ABr[2] = A1r * B0r - A1i * B0i;  ABi[2] = A1r * B0i + A1i * B0r;
        ABr[3] = A1r * B1r - A1i * B1i;  ABi[3] = A1r * B1i + A1i * B1r;
        const int gl = (t ^ (t >> 1)) & 31;
        const int t5 = (t >> 5) & 1;
        #pragma unroll
        for (int s = 0; s < 8; ++s) {          // s = (a<<2)|(bb<<1)|c
            const int a = s >> 2, bb = (s >> 1) & 1, c = s & 1;
            const int src = (a << 8) | ((a ^ bb) << 7) | ((bb ^ c) << 6)
                          | ((c ^ t5) << 5) | gl;
            const float2 v = sbuf[src];
            const float cRr = c ? C1r : C0r, cRi = c ? C1i : C0i;
            const float kr = ABr[a * 2 + bb] * cRr - ABi[a * 2 + bb] * cRi;
            const float ki = ABr[a * 2 + bb] * cRi + ABi[a * 2 + bb] * cRr;
            dr += kr * v.x - ki * v.y;
            di += kr * v.y + ki * v.x;
        }
    }

    // ---------- Phase 3: L1 lane-bit gates q3..q7 ----------
    #pragma unroll
    for (int q = 3; q <= 7; ++q) {
        const U2 u = ug[NQ + q];
        const int m = 1 << (8 - q);            // 32,16,8,4,2
        const int bit = (lane >> (8 - q)) & 1;
        const float a0r = bit ? u.r11 : u.r00, a0i = bit ? u.i11 : u.i00;
        const float b0r = bit ? u.r10 : u.r01, b0i = bit ? u.i10 : u.i01;
        const float pr = __shfl_xor(dr, m, 64);
        const float pi = __shfl_xor(di, m, 64);
        const float nr = a0r * dr - a0i * di + b0r * pr - b0i * pi;
        di = a0r * di + a0i * dr + b0r * pi + b0i * pr;
        dr = nr;
    }

    // ---------- Phase 4: L1 gate q8 (t bit 0) -> rank-2 coefficients ----------
    float uur, uui, vvr, vvi;                  // state = uu*W0(k) + vv*W1(k)
    {
        const U2 u8 = ug[NQ + 8];
        const float pr = __shfl_xor(dr, 1, 64);
        const float pi = __shfl_xor(di, 1, 64);
        const int t0 = t & 1;
        const float o1r = t0 ? pr : dr, o1i = t0 ? pi : di;
        const float o2r = t0 ? dr : pr, o2i = t0 ? di : pi;
        const float c1r = t0 ? u8.r10 : u8.r00, c1i = t0 ? u8.i10 : u8.i00;
        const float c2r = t0 ? u8.r11 : u8.r01, c2i = t0 ? u8.i11 : u8.i01;
        uur = c1r * o1r - c1i * o1i;  uui = c1r * o1i + c1i * o1r;
        vvr = c2r * o2r - c2i * o2i;  vvi = c2r * o2i + c2i * o2r;
    }

    // ---------- Phase 5: per-thread scalars -> LDS ----------
    const float A = uur * uur + uui * uui;
    const float B = vvr * vvr + vvi * vvi;
    const float C = 2.0f * (uur * vvr + uui * vvi);
    const float D = -2.0f * (uui * vvr - uur * vvi);
    const float ptot = A * scal[0] + B * scal[1] + C * scal[2] + D * scal[3];
    const float psg = (__popc(t) & 1) ? -1.0f : 1.0f;
    pbuf[t]  = ptot;
    abuf0[t] = psg * A;
    abuf1[t] = psg * B;
    abuf2[t] = psg * C;
    abuf3[t] = psg * D;
    __syncthreads();

    // ---------- Phase 6: one/two outputs per wave ----------
    // o1 = wv (outputs 0..7); o2: wave0 -> 8, waves 1..4 -> 9..12.
    {
        const int o = wv;                      // ptot-type output, 0..7
        float s = 0.0f;
        #pragma unroll
        for (int j = 0; j < 8; ++j) {
            const int tt = j * 64 + lane;
            const float v = pbuf[tt];
            s += (__popc(tt >> (8 - o)) & 1) ? -v : v;
        }
        #pragma unroll
        for (int off = 32; off; off >>= 1) s += __shfl_xor(s, off, 64);
        if (lane == 0) out[b * NQ + o] = s;
    }
    if (wv == 0) {                             // output 8 (full parity of t)
        float s = 0.0f;
        #pragma unroll
        for (int j = 0; j < 8; ++j) {
            const int tt = j * 64 + lane;
            const float v = pbuf[tt];
            s += (__popc(tt) & 1) ? -v : v;
        }
        #pragma unroll
        for (int off = 32; off; off >>= 1) s += __shfl_xor(s, off, 64);
        if (lane == 0) out[b * NQ + 8] = s;
    } else if (wv <= 4) {                      // outputs 9..12 (ABCD-type)
        const int idx = wv - 1;
        const float k0 = scal[4 + idx * 4 + 0];
        const float k1 = scal[4 + idx * 4 + 1];
        const float k2 = scal[4 + idx * 4 + 2];
        const float k3 = scal[4 + idx * 4 + 3];
        float s = 0.0f;
        #pragma unroll
        for (int j = 0; j < 8; ++j) {
            const int tt = j * 64 + lane;
            s += abuf0[tt] * k0 + abuf1[tt] * k1 + abuf2[tt] * k2 + abuf3[tt] * k3;
        }
        #pragma unroll
        for (int off = 32; off; off >>= 1) s += __shfl_xor(s, off, 64);
        if (lane == 0) out[b * NQ + 9 + idx] = s;
    }
}

extern "C" void kernel_launch(void* const* d_in, const int* in_sizes, int n_in,
                              void* d_out, int out_size, void* d_ws, size_t ws_size,
                              hipStream_t stream) {
    const float* x = (const float*)d_in[0];   // (512, 13) float32
    const float* w = (const float*)d_in[1];   // (2, 13, 3) float32
    float* out = (float*)d_out;               // (512, 13) float32
    qsim_kernel<<<NBATCH, TPB, 0, stream>>>(x, w, out);
}